// Round 15
// baseline (171.595 us; speedup 1.0000x reference)
//
#include <hip/hip_runtime.h>
#include <hip/hip_bf16.h>

#define NN 256
#define NH 8
#define NB 4
#define NPOS (NB * NN * NN)   // 262144 positions (b,n,m)

typedef float f32x4 __attribute__((ext_vector_type(4)));
typedef short bf16x8 __attribute__((ext_vector_type(8)));

static __device__ __forceinline__ short f2bf(float f) {
    __hip_bfloat16 h = __float2bfloat16(f);
    union { __hip_bfloat16 b; short s; } u; u.b = h; return u.s;
}

// ---------------------------------------------------------------------------
// Kernel 0 (init, parallel): per-lane B-fragments of W^T in global scratch:
// wfragG[l][s][j] = bf16(W[s*32+(l>>4)*8+j][l&15]), 0 for col>=8. ~2us.
// Also clears maskw.
// ---------------------------------------------------------------------------
__global__ void init_kernel(const float* __restrict__ W,
                            short* __restrict__ wfragG,
                            unsigned int* __restrict__ maskw)
{
    const int t = blockIdx.x * blockDim.x + threadIdx.x;   // 0..1023
    if (t < 8) maskw[t] = 0u;
    if (t >= 1024) return;
    const int l = t >> 4;               // lane 0..63
    const int s = t & 15;               // K-step 0..15
    const int r15 = l & 15;
    const int kg = l >> 4;
    bf16x8 v;
#pragma unroll
    for (int j = 0; j < 8; ++j) {
        const int kk = s * 32 + kg * 8 + j;
        v[j] = (r15 < 8) ? f2bf(W[(size_t)kk * NH + r15]) : (short)0;
    }
    *(bf16x8*)(&wfragG[(size_t)l * 128 + s * 8]) = v;
}

// ---------------------------------------------------------------------------
// Kernel 1 (MFMA): attn = sigmoid([NPOS x 512] @ W[512 x 8] + b)
// One wave = 16 positions, 16 x mfma_f32_16x16x32_bf16 over K=512.
// R14 conclusion: every pipeline-forcing trick (asm loads, sched_barriers,
// launch_bounds) is defeated by regalloc; and 10 structural variants all
// converge to ~3.3-3.4 TB/s logical read -- at/above the m13 copy ceiling's
// read side (6.29 TB/s counts fetch+write). So: accept the compiler's rolling
// schedule (plain loads), remove all overhead around it. Zero LDS, zero
// barriers in this kernel; wfrag from L2-hot global table (16 loads);
// 32 plain q/k dwordx4; cvt; 16 MFMA; store. 50% occupancy.
// ---------------------------------------------------------------------------
__global__ __launch_bounds__(256, 2) void attn_kernel(
    const float* __restrict__ q, const float* __restrict__ k,
    const short* __restrict__ wfragG, const float* __restrict__ bias,
    float* __restrict__ attn)
{
    const int tid = threadIdx.x;
    const int lane = tid & 63;
    const int wid = tid >> 6;
    const int r15 = lane & 15;          // A row / C col
    const int kg  = lane >> 4;          // k-group 0..3

    const int gwave = blockIdx.x * 4 + wid;      // 0..16383
    const int p0 = gwave * 16;

    const float* qrow = q + (size_t)(p0 + r15) * 256 + kg * 8;
    const float* krow = k + (size_t)(p0 + r15) * 256 + kg * 8;
    const short* wsrc = wfragG + (size_t)lane * 128;

    // W fragments: 16 contiguous bf16x8 (L2-hot, rolls with q/k loads)
    bf16x8 wf[16];
#pragma unroll
    for (int s = 0; s < 16; ++s)
        wf[s] = *(const bf16x8*)(wsrc + s * 8);

    // q/k fragment data: 32 dwordx4
    f32x4 qlo[8], qhi[8], klo[8], khi[8];
#pragma unroll
    for (int s = 0; s < 8; ++s) {
        qlo[s] = *(const f32x4*)(qrow + s * 32);
        qhi[s] = *(const f32x4*)(qrow + s * 32 + 4);
        klo[s] = *(const f32x4*)(krow + s * 32);
        khi[s] = *(const f32x4*)(krow + s * 32 + 4);
    }

    // convert to bf16 fragments
    bf16x8 afrag[16];
#pragma unroll
    for (int s = 0; s < 8; ++s) {
        afrag[s][0] = f2bf(qlo[s].x); afrag[s][1] = f2bf(qlo[s].y);
        afrag[s][2] = f2bf(qlo[s].z); afrag[s][3] = f2bf(qlo[s].w);
        afrag[s][4] = f2bf(qhi[s].x); afrag[s][5] = f2bf(qhi[s].y);
        afrag[s][6] = f2bf(qhi[s].z); afrag[s][7] = f2bf(qhi[s].w);
        afrag[8+s][0] = f2bf(klo[s].x); afrag[8+s][1] = f2bf(klo[s].y);
        afrag[8+s][2] = f2bf(klo[s].z); afrag[8+s][3] = f2bf(klo[s].w);
        afrag[8+s][4] = f2bf(khi[s].x); afrag[8+s][5] = f2bf(khi[s].y);
        afrag[8+s][6] = f2bf(khi[s].z); afrag[8+s][7] = f2bf(khi[s].w);
    }

    f32x4 acc = {0.f, 0.f, 0.f, 0.f};
#pragma unroll
    for (int s = 0; s < 16; ++s)
        acc = __builtin_amdgcn_mfma_f32_16x16x32_bf16(afrag[s], wf[s], acc,
                                                      0, 0, 0);

    // epilogue: C[row=kg*4+i][col=r15], cols 0..7 valid (verified R12)
    if (r15 < 8) {
        const float bb = bias[r15];
#pragma unroll
        for (int i = 0; i < 4; ++i) {
            const int pos = p0 + kg * 4 + i;
            const float s = 1.f / (1.f + __expf(-(acc[i] + bb)));
            attn[(size_t)pos * NH + r15] = s;
        }
    }
}

// ---------------------------------------------------------------------------
// Kernel 2: dim2_mask union of top-k / bottom-k indices (exact rank count,
// matches jax.lax.top_k stable tie-breaking). Register-accumulated selection,
// ballot + 2 atomicOr per wave; 64 publisher blocks seed the mask per-task;
// everyone early-exits on full mask via volatile loads (monotonic bits =>
// stale reads are safe).
// ---------------------------------------------------------------------------
__global__ __launch_bounds__(256) void topk_kernel(
    const float* __restrict__ attn, const float* __restrict__ m1,
    const float* __restrict__ m2, unsigned int* __restrict__ maskw)
{
    __shared__ __align__(16) float a[NN];
    __shared__ int snotfull;
    const int tid = threadIdx.x;
    const int T = 2 * NB * NN * NH;   // 16384 tasks
    const bool publisher = (blockIdx.x < 64);
    const volatile unsigned int* vmask = maskw;
    bool selAcc = false;
    bool broke = false;

    for (int t = blockIdx.x; t < T; t += gridDim.x) {
        if (t != (int)blockIdx.x) {
            if (tid == 0) snotfull = 0;
            __syncthreads();
            if (tid < 8 && vmask[tid] != 0xFFFFFFFFu) snotfull = 1;
            __syncthreads();
            if (!snotfull) { broke = true; break; }
        }

        const int variant = t >> 13;
        const int r = t & 8191;
        const int h = r & 7;
        const int n = (r >> 3) & 255;
        const int b = r >> 11;
        const size_t rowBase = ((size_t)(b * NN + n)) * NN;
        const float* mk = variant ? m2 : m1;
        const int kt = variant ? 128 : 64;
        const int kb = 64;

        a[tid] = attn[(rowBase + tid) * NH + h] * mk[rowBase + tid];
        __syncthreads();

        const float av = a[tid];
        int gt = 0, lt = 0, el = 0;
#pragma unroll 8
        for (int u4 = 0; u4 < NN / 4; ++u4) {
            const f32x4 w = *reinterpret_cast<const f32x4*>(&a[u4 * 4]);
            const int u = u4 * 4;
            gt += (w.x > av) + (w.y > av) + (w.z > av) + (w.w > av);
            lt += (w.x < av) + (w.y < av) + (w.z < av) + (w.w < av);
            el += ((w.x == av) & (u + 0 < tid)) + ((w.y == av) & (u + 1 < tid))
                + ((w.z == av) & (u + 2 < tid)) + ((w.w == av) & (u + 3 < tid));
        }
        const bool sel = ((gt + el) < kt) || ((lt + el) < kb);
        selAcc |= sel;

        if (publisher) {
            const unsigned long long bal = __ballot(sel);
            if ((tid & 63) == 0) {
                const int w = tid >> 6;
                atomicOr(&maskw[w * 2 + 0], (unsigned int)(bal & 0xFFFFFFFFull));
                atomicOr(&maskw[w * 2 + 1], (unsigned int)(bal >> 32));
            }
        }
        __syncthreads();
    }

    if (!broke && !publisher) {
        const unsigned long long bal = __ballot(selAcc);
        if ((tid & 63) == 0) {
            const int w = tid >> 6;
            atomicOr(&maskw[w * 2 + 0], (unsigned int)(bal & 0xFFFFFFFFull));
            atomicOr(&maskw[w * 2 + 1], (unsigned int)(bal >> 32));
        }
    }
}

// ---------------------------------------------------------------------------
// Kernel 3: out *= (m1+m2) * dim2_mask[m], in place, float4 over H.
// ---------------------------------------------------------------------------
__global__ __launch_bounds__(256) void finalize_kernel(
    float* __restrict__ out, const float* __restrict__ m1,
    const float* __restrict__ m2, const unsigned int* __restrict__ maskw)
{
    const int total = NPOS * 2;       // float4 units (H=8 -> 2 per position)
    for (int i4 = blockIdx.x * blockDim.x + threadIdx.x; i4 < total;
         i4 += gridDim.x * blockDim.x) {
        const int m = (i4 >> 1) & 255;
        const int bn = i4 >> 9;
        const float bit = ((maskw[m >> 5] >> (m & 31)) & 1u) ? 1.f : 0.f;
        const size_t mi = (size_t)bn * NN + m;
        const float scale = (m1[mi] + m2[mi]) * bit;
        f32x4 v = reinterpret_cast<f32x4*>(out)[i4];
        v.x *= scale; v.y *= scale; v.z *= scale; v.w *= scale;
        reinterpret_cast<f32x4*>(out)[i4] = v;
    }
}

extern "C" void kernel_launch(void* const* d_in, const int* in_sizes, int n_in,
                              void* d_out, int out_size, void* d_ws, size_t ws_size,
                              hipStream_t stream) {
    const float* q    = (const float*)d_in[0];
    const float* kk   = (const float*)d_in[1];
    const float* m1   = (const float*)d_in[2];
    const float* m2   = (const float*)d_in[3];
    const float* W    = (const float*)d_in[4];
    const float* bias = (const float*)d_in[5];
    float* out = (float*)d_out;

    unsigned int* maskw = (unsigned int*)d_ws;
    short* wfragG = (short*)((char*)d_ws + 256);   // 16KB fragment table

    hipLaunchKernelGGL(init_kernel, dim3(4), dim3(256), 0, stream,
                       W, wfragG, maskw);
    // 4096 blocks * 4 waves = 16384 waves; 16 positions each = NPOS exactly
    hipLaunchKernelGGL(attn_kernel, dim3(4096), dim3(256), 0, stream,
                       q, kk, wfragG, bias, out);
    hipLaunchKernelGGL(topk_kernel, dim3(1024), dim3(256), 0, stream,
                       out, m1, m2, maskw);
    hipLaunchKernelGGL(finalize_kernel, dim3(2048), dim3(256), 0, stream,
                       out, m1, m2, maskw);
}

// Round 17
// 149.500 us; speedup vs baseline: 1.1478x; 1.1478x over previous
//
#include <hip/hip_runtime.h>
#include <hip/hip_bf16.h>

#define NN 256
#define NH 8
#define NB 4
#define NPOS (NB * NN * NN)   // 262144 positions (b,n,m)

typedef float f32x4 __attribute__((ext_vector_type(4)));
typedef short bf16x8 __attribute__((ext_vector_type(8)));
typedef short bf16x4 __attribute__((ext_vector_type(4)));

static __device__ __forceinline__ short f2bf(float f) {
    __hip_bfloat16 h = __float2bfloat16(f);
    union { __hip_bfloat16 b; short s; } u; u.b = h; return u.s;
}

// ---------------------------------------------------------------------------
// Kernel 0 (init, parallel): per-lane B-fragments of W^T in global scratch:
// wfragG[l][s][j] = bf16(W[s*32+(l>>4)*8+j][l&15]), 0 for col>=8. ~2us.
// Steps s=0..7 cover ft dims 0..255 (q); s=8..15 cover dims 256..511 (k).
// Also clears maskw.
// ---------------------------------------------------------------------------
__global__ void init_kernel(const float* __restrict__ W,
                            short* __restrict__ wfragG,
                            unsigned int* __restrict__ maskw)
{
    const int t = blockIdx.x * blockDim.x + threadIdx.x;   // 0..1023
    if (t < 8) maskw[t] = 0u;
    if (t >= 1024) return;
    const int l = t >> 4;               // lane 0..63
    const int s = t & 15;               // K-step 0..15
    const int r15 = l & 15;
    const int kg = l >> 4;
    bf16x8 v;
#pragma unroll
    for (int j = 0; j < 8; ++j) {
        const int kk = s * 32 + kg * 8 + j;
        v[j] = (r15 < 8) ? f2bf(W[(size_t)kk * NH + r15]) : (short)0;
    }
    *(bf16x8*)(&wfragG[(size_t)l * 128 + s * 8]) = v;
}

// ---------------------------------------------------------------------------
// Kernel 1 (MFMA + contiguous reads): attn = sigmoid([NPOSx512]@W[512x8]+b)
// Contiguity experiment, pairing FIXED from R16: a q row is 256 dims = 8
// K-steps. q supplies steps 0..7 (afq[s] x wf[s]); k supplies steps 8..15
// (afk[s] x wf[s+8]). Global reads are whole contiguous 1KB rows per
// instruction (exact m13 copy shape); fp32->bf16 cvt in-reg; wave-private
// LDS (stride 528B, 16B-aligned rows); ds_read_b128 fragments; 16 MFMA.
// No barriers (wave-private buffer; DS ops in-order within a wave; C++
// aliasing preserves read-before-overwrite order).
// ---------------------------------------------------------------------------
__global__ __launch_bounds__(256, 3) void attn_kernel(
    const float* __restrict__ q, const float* __restrict__ k,
    const short* __restrict__ wfragG, const float* __restrict__ bias,
    float* __restrict__ attn)
{
    __shared__ __align__(16) char lds[4 * 16 * 528];   // 33792B: 4 waves
    const int tid = threadIdx.x;
    const int lane = tid & 63;
    const int wid = tid >> 6;
    const int r15 = lane & 15;          // A row / C col
    const int kg  = lane >> 4;          // k-group 0..3

    const int gwave = blockIdx.x * 4 + wid;      // 0..16383
    const int p0 = gwave * 16;

    char* myL = &lds[wid * 16 * 528];

    // ---- stage q rows (contiguous 1KB/instr), cvt to bf16, LDS write ----
#pragma unroll
    for (int i = 0; i < 16; ++i) {
        const f32x4 v = *(const f32x4*)(q + (size_t)(p0 + i) * 256 + lane * 4);
        bf16x4 h;
        h[0] = f2bf(v.x); h[1] = f2bf(v.y); h[2] = f2bf(v.z); h[3] = f2bf(v.w);
        *(bf16x4*)(myL + i * 528 + lane * 8) = h;
    }

    // W fragments while q settles (L2-hot)
    const short* wsrc = wfragG + (size_t)lane * 128;
    bf16x8 wf[16];
#pragma unroll
    for (int s = 0; s < 16; ++s)
        wf[s] = *(const bf16x8*)(wsrc + s * 8);

    asm volatile("s_waitcnt lgkmcnt(0)" ::: "memory");
    __builtin_amdgcn_sched_barrier(0);

    // ---- q fragments (steps 0..7): row r15, bytes s*64 + kg*16 ----
    bf16x8 afq[8];
#pragma unroll
    for (int s = 0; s < 8; ++s)
        afq[s] = *(const bf16x8*)(myL + r15 * 528 + (s * 64 + kg * 16));

    f32x4 acc = {0.f, 0.f, 0.f, 0.f};
#pragma unroll
    for (int s = 0; s < 8; ++s)
        acc = __builtin_amdgcn_mfma_f32_16x16x32_bf16(afq[s], wf[s], acc, 0, 0, 0);

    // ---- stage k rows (contiguous), cvt, LDS write (reuse same buffer) ----
#pragma unroll
    for (int i = 0; i < 16; ++i) {
        const f32x4 v = *(const f32x4*)(k + (size_t)(p0 + i) * 256 + lane * 4);
        bf16x4 h;
        h[0] = f2bf(v.x); h[1] = f2bf(v.y); h[2] = f2bf(v.z); h[3] = f2bf(v.w);
        *(bf16x4*)(myL + i * 528 + lane * 8) = h;
    }
    asm volatile("s_waitcnt lgkmcnt(0)" ::: "memory");
    __builtin_amdgcn_sched_barrier(0);

    // ---- k fragments (steps 8..15) ----
    bf16x8 afk[8];
#pragma unroll
    for (int s = 0; s < 8; ++s)
        afk[s] = *(const bf16x8*)(myL + r15 * 528 + (s * 64 + kg * 16));
#pragma unroll
    for (int s = 0; s < 8; ++s)
        acc = __builtin_amdgcn_mfma_f32_16x16x32_bf16(afk[s], wf[s + 8], acc, 0, 0, 0);

    // epilogue: C[row=kg*4+i][col=r15], cols 0..7 valid (verified R12)
    if (r15 < 8) {
        const float bb = bias[r15];
#pragma unroll
        for (int i = 0; i < 4; ++i) {
            const int pos = p0 + kg * 4 + i;
            const float s = 1.f / (1.f + __expf(-(acc[i] + bb)));
            attn[(size_t)pos * NH + r15] = s;
        }
    }
}

// ---------------------------------------------------------------------------
// Kernel 2: dim2_mask union of top-k / bottom-k indices (exact rank count,
// matches jax.lax.top_k stable tie-breaking). Register-accumulated selection,
// ballot + 2 atomicOr per wave; 64 publisher blocks seed the mask per-task;
// everyone early-exits on full mask via volatile loads (monotonic bits =>
// stale reads are safe).
// ---------------------------------------------------------------------------
__global__ __launch_bounds__(256) void topk_kernel(
    const float* __restrict__ attn, const float* __restrict__ m1,
    const float* __restrict__ m2, unsigned int* __restrict__ maskw)
{
    __shared__ __align__(16) float a[NN];
    __shared__ int snotfull;
    const int tid = threadIdx.x;
    const int T = 2 * NB * NN * NH;   // 16384 tasks
    const bool publisher = (blockIdx.x < 64);
    const volatile unsigned int* vmask = maskw;
    bool selAcc = false;
    bool broke = false;

    for (int t = blockIdx.x; t < T; t += gridDim.x) {
        if (t != (int)blockIdx.x) {
            if (tid == 0) snotfull = 0;
            __syncthreads();
            if (tid < 8 && vmask[tid] != 0xFFFFFFFFu) snotfull = 1;
            __syncthreads();
            if (!snotfull) { broke = true; break; }
        }

        const int variant = t >> 13;
        const int r = t & 8191;
        const int h = r & 7;
        const int n = (r >> 3) & 255;
        const int b = r >> 11;
        const size_t rowBase = ((size_t)(b * NN + n)) * NN;
        const float* mk = variant ? m2 : m1;
        const int kt = variant ? 128 : 64;
        const int kb = 64;

        a[tid] = attn[(rowBase + tid) * NH + h] * mk[rowBase + tid];
        __syncthreads();

        const float av = a[tid];
        int gt = 0, lt = 0, el = 0;
#pragma unroll 8
        for (int u4 = 0; u4 < NN / 4; ++u4) {
            const f32x4 w = *reinterpret_cast<const f32x4*>(&a[u4 * 4]);
            const int u = u4 * 4;
            gt += (w.x > av) + (w.y > av) + (w.z > av) + (w.w > av);
            lt += (w.x < av) + (w.y < av) + (w.z < av) + (w.w < av);
            el += ((w.x == av) & (u + 0 < tid)) + ((w.y == av) & (u + 1 < tid))
                + ((w.z == av) & (u + 2 < tid)) + ((w.w == av) & (u + 3 < tid));
        }
        const bool sel = ((gt + el) < kt) || ((lt + el) < kb);
        selAcc |= sel;

        if (publisher) {
            const unsigned long long bal = __ballot(sel);
            if ((tid & 63) == 0) {
                const int w = tid >> 6;
                atomicOr(&maskw[w * 2 + 0], (unsigned int)(bal & 0xFFFFFFFFull));
                atomicOr(&maskw[w * 2 + 1], (unsigned int)(bal >> 32));
            }
        }
        __syncthreads();
    }

    if (!broke && !publisher) {
        const unsigned long long bal = __ballot(selAcc);
        if ((tid & 63) == 0) {
            const int w = tid >> 6;
            atomicOr(&maskw[w * 2 + 0], (unsigned int)(bal & 0xFFFFFFFFull));
            atomicOr(&maskw[w * 2 + 1], (unsigned int)(bal >> 32));
        }
    }
}

// ---------------------------------------------------------------------------
// Kernel 3: out *= (m1+m2) * dim2_mask[m], in place, float4 over H.
// ---------------------------------------------------------------------------
__global__ __launch_bounds__(256) void finalize_kernel(
    float* __restrict__ out, const float* __restrict__ m1,
    const float* __restrict__ m2, const unsigned int* __restrict__ maskw)
{
    const int total = NPOS * 2;       // float4 units (H=8 -> 2 per position)
    for (int i4 = blockIdx.x * blockDim.x + threadIdx.x; i4 < total;
         i4 += gridDim.x * blockDim.x) {
        const int m = (i4 >> 1) & 255;
        const int bn = i4 >> 9;
        const float bit = ((maskw[m >> 5] >> (m & 31)) & 1u) ? 1.f : 0.f;
        const size_t mi = (size_t)bn * NN + m;
        const float scale = (m1[mi] + m2[mi]) * bit;
        f32x4 v = reinterpret_cast<f32x4*>(out)[i4];
        v.x *= scale; v.y *= scale; v.z *= scale; v.w *= scale;
        reinterpret_cast<f32x4*>(out)[i4] = v;
    }
}

extern "C" void kernel_launch(void* const* d_in, const int* in_sizes, int n_in,
                              void* d_out, int out_size, void* d_ws, size_t ws_size,
                              hipStream_t stream) {
    const float* q    = (const float*)d_in[0];
    const float* kk   = (const float*)d_in[1];
    const float* m1   = (const float*)d_in[2];
    const float* m2   = (const float*)d_in[3];
    const float* W    = (const float*)d_in[4];
    const float* bias = (const float*)d_in[5];
    float* out = (float*)d_out;

    unsigned int* maskw = (unsigned int*)d_ws;
    short* wfragG = (short*)((char*)d_ws + 256);   // 16KB fragment table

    hipLaunchKernelGGL(init_kernel, dim3(4), dim3(256), 0, stream,
                       W, wfragG, maskw);
    // 4096 blocks * 4 waves = 16384 waves; 16 positions each = NPOS exactly
    hipLaunchKernelGGL(attn_kernel, dim3(4096), dim3(256), 0, stream,
                       q, kk, wfragG, bias, out);
    hipLaunchKernelGGL(topk_kernel, dim3(1024), dim3(256), 0, stream,
                       out, m1, m2, maskw);
    hipLaunchKernelGGL(finalize_kernel, dim3(2048), dim3(256), 0, stream,
                       out, m1, m2, maskw);
}